// Round 1
// baseline (10835.764 us; speedup 1.0000x reference)
//
#include <hip/hip_runtime.h>

typedef _Float16 f16;
typedef _Float16 f16x8 __attribute__((ext_vector_type(8)));
typedef float f32x4 __attribute__((ext_vector_type(4)));

#define STEPS 512
#define BATCHN 256
#define HID 1024
#define EMBN 100
#define KTOT 1152
#define XPAD 128
#define NBLK 256

__device__ __forceinline__ float sigm(float x){ return 1.f/(1.f+__expf(-x)); }
__device__ __forceinline__ float tanh_f(float x){
    float e = __expf(2.f*fabsf(x));
    float r = 1.f - 2.f/(e+1.f);
    return x >= 0.f ? r : -r;
}

// Pack W_h (1024 rows) + W_x (100 rows) + zero pad -> WT[4096][1152] fp16 hi/lo,
// column J = cg*64 + gate*16 + ul  (unit u = cg*16+ul). Also pack bias[J].
__global__ void pack_w(const float* __restrict__ Whi_, const float* __restrict__ Whf_,
                       const float* __restrict__ Who_, const float* __restrict__ Whc_,
                       const float* __restrict__ Wxi_, const float* __restrict__ Wxf_,
                       const float* __restrict__ Wxo_, const float* __restrict__ Wxc_,
                       const float* __restrict__ bi_, const float* __restrict__ bf_,
                       const float* __restrict__ bo_, const float* __restrict__ bc_,
                       f16* __restrict__ WThi, f16* __restrict__ WTlo, float* __restrict__ biasP)
{
    int J = blockIdx.x;                 // 0..4095
    int cg = J >> 6, g = (J >> 4) & 3, ul = J & 15;
    int u = cg*16 + ul;
    const float* Wh = (g==0)?Whi_:(g==1)?Whf_:(g==2)?Who_:Whc_;
    const float* Wx = (g==0)?Wxi_:(g==1)?Wxf_:(g==2)?Wxo_:Wxc_;
    for (int k = threadIdx.x; k < KTOT; k += blockDim.x){
        float v = 0.f;
        if (k < 1024)       v = Wh[(size_t)k*HID + u];
        else if (k < 1124)  v = Wx[(size_t)(k-1024)*HID + u];
        f16 hi = (f16)v;
        WThi[(size_t)J*KTOT + k] = hi;
        WTlo[(size_t)J*KTOT + k] = (f16)(v - (float)hi);
    }
    if (threadIdx.x == 0){
        const float* bb = (g==0)?bi_:(g==1)?bf_:(g==2)?bo_:bc_;
        biasP[J] = bb[u];
    }
}

// X[t][row][0..127] = fp16(emb[tokens[row][t]][kx]) (zero padded 100..127)
__global__ void pack_x(const int* __restrict__ tokens, const float* __restrict__ emb,
                       f16* __restrict__ Xbuf)
{
    int bid = blockIdx.x;               // t*256 + row
    int t = bid >> 8, row = bid & 255;
    int tok = tokens[(size_t)row*STEPS + t];
    int kx = threadIdx.x;               // 0..127
    float v = (kx < EMBN) ? emb[(size_t)tok*EMBN + kx] : 0.f;
    Xbuf[(size_t)bid*XPAD + kx] = (f16)v;
}

__global__ void pack_h0(const float* __restrict__ H0, f16* __restrict__ Hb)
{
    int i = blockIdx.x*blockDim.x + threadIdx.x;
    if (i < BATCHN*HID) Hb[i] = (f16)H0[i];
}

// Persistent LSTM: 256 blocks (4 batch-groups x 64 col-groups) x 256 threads.
// Weights in VGPRs (hi/lo fp16), C in registers, H ping-pongs fp16 in global,
// one device-scope grid barrier per step.
__global__ __launch_bounds__(256, 1) void lstm_main(
    const f16* __restrict__ WThi, const f16* __restrict__ WTlo,
    const f16* __restrict__ Xbuf, const float* __restrict__ biasP,
    const float* __restrict__ C0, f16* __restrict__ Ha, f16* __restrict__ Hb,
    const float* __restrict__ dw, const float* __restrict__ db,
    float* __restrict__ out, unsigned int* __restrict__ ctr)
{
    const int bid = blockIdx.x;
    const int bg = bid & 3, cg = bid >> 2;
    const int tid = threadIdx.x;
    const int w = tid >> 6, l = tid & 63, lr = l & 15, lhi = l >> 4;

    __shared__ f32x4 red[4][4][4][64];   // [owner_rt][giver_wave][gate][lane], 64KB

    // ---- load persistent B fragments: 9 k-tiles x {hi,lo} x 4 gate-cols ----
    f16x8 Bf[9][2][4];
    #pragma unroll
    for (int kt = 0; kt < 9; kt++){
        int k0 = (w*9 + kt)*32 + lhi*8;
        #pragma unroll
        for (int n = 0; n < 4; n++){
            size_t off = (size_t)(cg*64 + n*16 + lr)*KTOT + k0;
            Bf[kt][0][n] = *(const f16x8*)(WThi + off);
            Bf[kt][1][n] = *(const f16x8*)(WTlo + off);
        }
    }
    float bs[4];
    #pragma unroll
    for (int g = 0; g < 4; g++) bs[g] = biasP[cg*64 + g*16 + lr];

    const int rowbase = bg*64 + w*16 + lhi*4;   // kept rowtile = global rt w
    const int unit = cg*16 + lr;
    float Cr[4];
    #pragma unroll
    for (int r = 0; r < 4; r++) Cr[r] = C0[(size_t)(rowbase + r)*HID + unit];

    for (int t = 0; t < STEPS; t++){
        const f16* Hrd = (t & 1) ? Hb : Ha;
        f16*       Hwr = (t & 1) ? Ha : Hb;

        f32x4 acc[4][4];
        #pragma unroll
        for (int q = 0; q < 4; q++)
            #pragma unroll
            for (int n = 0; n < 4; n++) acc[q][n] = (f32x4){0.f,0.f,0.f,0.f};

        #pragma unroll
        for (int kt = 0; kt < 9; kt++){
            int k0 = (w*9 + kt)*32;
            f16x8 Af[4];
            if (k0 < 1024){
                const f16* base = Hrd + k0 + lhi*8;
                #pragma unroll
                for (int q = 0; q < 4; q++){
                    int rtg = (w + q) & 3;            // local q=0 -> global rt w
                    Af[q] = *(const f16x8*)(base + (size_t)(bg*64 + rtg*16 + lr)*HID);
                }
            } else {
                const f16* base = Xbuf + (size_t)t*BATCHN*XPAD + (k0 - 1024) + lhi*8;
                #pragma unroll
                for (int q = 0; q < 4; q++){
                    int rtg = (w + q) & 3;
                    Af[q] = *(const f16x8*)(base + (size_t)(bg*64 + rtg*16 + lr)*XPAD);
                }
            }
            #pragma unroll
            for (int q = 0; q < 4; q++)
                #pragma unroll
                for (int n = 0; n < 4; n++){
                    acc[q][n] = __builtin_amdgcn_mfma_f32_16x16x32_f16(Af[q], Bf[kt][0][n], acc[q][n], 0,0,0);
                    acc[q][n] = __builtin_amdgcn_mfma_f32_16x16x32_f16(Af[q], Bf[kt][1][n], acc[q][n], 0,0,0);
                }
        }

        // ---- cross-wave K reduction (give away local tiles q=1..3) ----
        #pragma unroll
        for (int q = 1; q < 4; q++){
            int owner = (w + q) & 3;
            #pragma unroll
            for (int n = 0; n < 4; n++) red[owner][w][n][l] = acc[q][n];
        }
        __syncthreads();
        #pragma unroll
        for (int q = 1; q < 4; q++){
            int giver = (w + q) & 3;
            #pragma unroll
            for (int n = 0; n < 4; n++) acc[0][n] += red[w][giver][n][l];
        }

        // ---- elementwise epilogue: lane holds i,f,o,c of `unit` for 4 rows ----
        #pragma unroll
        for (int r = 0; r < 4; r++){
            float gi = acc[0][0][r] + bs[0];
            float gf = acc[0][1][r] + bs[1];
            float go = acc[0][2][r] + bs[2];
            float gc = acc[0][3][r] + bs[3];
            float I = sigm(gi), F = sigm(gf), O = sigm(go), G = tanh_f(gc);
            float c = F*Cr[r] + I*G;
            Cr[r] = c;
            float h = O*tanh_f(c);
            Hwr[(size_t)(rowbase + r)*HID + unit] = (f16)h;
        }

        // ---- grid barrier (release H writes, acquire for next step reads) ----
        __syncthreads();
        if (tid == 0){
            __hip_atomic_fetch_add(ctr, 1u, __ATOMIC_RELEASE, __HIP_MEMORY_SCOPE_AGENT);
            unsigned int target = (unsigned int)(NBLK*(t+1));
            unsigned int guard = 0;
            while (__hip_atomic_load(ctr, __ATOMIC_RELAXED, __HIP_MEMORY_SCOPE_AGENT) < target){
                __builtin_amdgcn_s_sleep(2);
                if (++guard > 4000000u) break;   // bounded: fail loud, not hung
            }
            (void)__hip_atomic_load(ctr, __ATOMIC_ACQUIRE, __HIP_MEMORY_SCOPE_AGENT);
        }
        __syncthreads();
    }

    // ---- final dense: H(final, in Ha) @ dense_w + dense_b -> out[256][2] ----
    if (cg == 0){
        const f16* Hf = Ha;                     // t=511 wrote Ha
        int rl = tid >> 2, j = (tid >> 1) & 1, half = tid & 1;
        int row = bg*64 + rl;
        const f16* hrow = Hf + (size_t)row*HID + half*512;
        float s = 0.f;
        for (int v = 0; v < 64; v++){
            f16x8 h8 = *(const f16x8*)(hrow + v*8);
            #pragma unroll
            for (int e = 0; e < 8; e++)
                s += (float)h8[e] * dw[(size_t)(half*512 + v*8 + e)*2 + j];
        }
        s += __shfl_xor(s, 1, 64);
        if (half == 0) out[(size_t)row*2 + j] = s + db[j];
    }
}

extern "C" void kernel_launch(void* const* d_in, const int* in_sizes, int n_in,
                              void* d_out, int out_size, void* d_ws, size_t ws_size,
                              hipStream_t stream)
{
    const int*   tokens = (const int*)d_in[0];
    const float* H0  = (const float*)d_in[1];
    const float* C0  = (const float*)d_in[2];
    const float* Wxi = (const float*)d_in[3];
    const float* Whi = (const float*)d_in[4];
    const float* bi  = (const float*)d_in[5];
    const float* Wxf = (const float*)d_in[6];
    const float* Whf = (const float*)d_in[7];
    const float* bf  = (const float*)d_in[8];
    const float* Wxo = (const float*)d_in[9];
    const float* Who = (const float*)d_in[10];
    const float* bo  = (const float*)d_in[11];
    const float* Wxc = (const float*)d_in[12];
    const float* Whc = (const float*)d_in[13];
    const float* bc  = (const float*)d_in[14];
    const float* emb = (const float*)d_in[15];
    const float* dw  = (const float*)d_in[16];
    const float* db  = (const float*)d_in[17];
    float* out = (float*)d_out;

    char* ws = (char*)d_ws;
    size_t off = 0;
    auto alloc = [&](size_t bytes){ void* p = ws + off; off += (bytes + 255) & ~(size_t)255; return p; };
    f16* WThi = (f16*)alloc((size_t)4096*KTOT*2);
    f16* WTlo = (f16*)alloc((size_t)4096*KTOT*2);
    f16* Xbuf = (f16*)alloc((size_t)STEPS*BATCHN*XPAD*2);
    f16* Ha   = (f16*)alloc((size_t)BATCHN*HID*2);
    f16* Hb   = (f16*)alloc((size_t)BATCHN*HID*2);
    float* biasP = (float*)alloc(4096*sizeof(float));
    unsigned int* ctr = (unsigned int*)alloc(64);
    if (off > ws_size) return;   // workspace too small: fail loud

    hipMemsetAsync(ctr, 0, 64, stream);
    pack_w<<<4096, 256, 0, stream>>>(Whi,Whf,Who,Whc, Wxi,Wxf,Wxo,Wxc, bi,bf,bo,bc,
                                     WThi, WTlo, biasP);
    pack_x<<<STEPS*BATCHN, 128, 0, stream>>>(tokens, emb, Xbuf);
    pack_h0<<<(BATCHN*HID + 255)/256, 256, 0, stream>>>(H0, Ha);
    lstm_main<<<NBLK, 256, 0, stream>>>(WThi, WTlo, Xbuf, biasP, C0, Ha, Hb,
                                        dw, db, out, ctr);
}